// Round 2
// baseline (1387.084 us; speedup 1.0000x reference)
//
#include <hip/hip_runtime.h>
#include <hip/hip_bf16.h>

// BatchedDiffPool on MI355X. Inputs f32, outputs f32; internal compute bf16
// via v_mfma_f32_16x16x32_bf16 (comparison threshold is bf16-scaled).
//
// Pipeline:
//  h1=x@We, h2=x@Wa -> f-vectors -> denoms (one adj pass) ->
//  z_l = elu(P1@h1/d1 + h1)  (fused, N=128 => one n-block)
//  Y2  = P2@h2 (f32) -> row softmax(elu(Y2/d2+h2)) = s_l -> d_out(f32)+ws(bf16)
//  t = adj@s_l ; anext = s_l^T@t ; xnext = s_l^T@z_l  (split-K, f32 atomics
//  straight into d_out)

#define DI __device__ __forceinline__

typedef __attribute__((ext_vector_type(8))) short short8;
typedef __attribute__((ext_vector_type(4))) float f32x4;

static DI float bf2f(short s) {
    union { unsigned u; float f; } c;
    c.u = ((unsigned)(unsigned short)s) << 16;
    return c.f;
}
static DI short f2bf(float f) {
    union { float f; unsigned u; } c; c.f = f;
    unsigned r = (c.u + 0x7FFFu + ((c.u >> 16) & 1u)) >> 16; // RTN-even
    return (short)(unsigned short)r;
}
// load 8 consecutive elements as bf16 shorts; F32=1 converts from float
template <int F32>
static DI short8 ld8(const void* base, size_t off) {
    if (F32) {
        const float* p = (const float*)base + off;
        f32x4 a = *(const f32x4*)p;
        f32x4 b = *(const f32x4*)(p + 4);
        short8 v;
        #pragma unroll
        for (int e = 0; e < 4; e++) { v[e] = f2bf(a[e]); v[4 + e] = f2bf(b[e]); }
        return v;
    } else {
        return *(const short8*)((const short*)base + off);
    }
}
// load 8 consecutive elements as floats
template <int F32>
static DI void ld8f(const void* base, size_t off, float* out) {
    if (F32) {
        const float* p = (const float*)base + off;
        f32x4 a = *(const f32x4*)p;
        f32x4 b = *(const f32x4*)(p + 4);
        #pragma unroll
        for (int e = 0; e < 4; e++) { out[e] = a[e]; out[4 + e] = b[e]; }
    } else {
        short8 v = *(const short8*)((const short*)base + off);
        #pragma unroll
        for (int e = 0; e < 8; e++) out[e] = bf2f(v[e]);
    }
}
static DI float wred_sum(float v) {
    #pragma unroll
    for (int o = 32; o > 0; o >>= 1) v += __shfl_down(v, o, 64);
    return v;
}
static DI float wred_max(float v) {
    #pragma unroll
    for (int o = 32; o > 0; o >>= 1) v = fmaxf(v, __shfl_down(v, o, 64));
    return v;
}

// ---------------------------------------------------------------------------
// Generic 256-thread (4-wave, 2x2) MFMA GEMM tile kernel. BN fixed at 128.
// AMODE: 0 = A row-major [M][lda]
//        1 = A generated: P_ik = adj_ik * exp(leakyrelu(f1[i]+f2[k], 0.2))
//        2 = A = S^T where S is row-major [K][lda] (A[m][k]=S[k][m])
// EPI:   0 = store f32 C       1 = store bf16 C
//        2 = GAT1 fused: bf16( elu(acc/denom[row] + Hadd[row][col]) )
//        3 = atomicAdd into f32 C (split-K)
// AF32/BF32: element type of A/B (1 = float32, 0 = bf16)
// grid: x = n-block, y = m-block, z = k-split (k range = z*kcount .. +kcount)
// ---------------------------------------------------------------------------
template <int BM, int BK, int AMODE, int EPI, int AF32, int BF32>
__launch_bounds__(256)
__global__ void gemm_k(const void* __restrict__ A, const void* __restrict__ B,
                       void* __restrict__ C, int lda, int ldb, int ldc, int kcount,
                       const float* __restrict__ f1, const float* __restrict__ f2,
                       const float* __restrict__ denom, const short* __restrict__ Hadd,
                       int ldh) {
    __shared__ short As[BM][BK + 8];     // +8 shorts: 144B row stride
    __shared__ short Bs[128][BK + 8];    // stored transposed: Bs[n][k]

    const int tid  = threadIdx.x;
    const int lane = tid & 63;
    const int w    = tid >> 6;
    const int wr   = w >> 1, wc = w & 1;
    const int i0   = blockIdx.y * BM;
    const int n0   = blockIdx.x * 128;
    const int k0   = blockIdx.z * kcount;

    const int FM = BM / 32;
    f32x4 acc[FM][4];
    #pragma unroll
    for (int m = 0; m < FM; m++)
        #pragma unroll
        for (int n = 0; n < 4; n++) acc[m][n] = (f32x4){0.f, 0.f, 0.f, 0.f};

    for (int ks = k0; ks < k0 + kcount; ks += BK) {
        __syncthreads();
        // ---- stage A ----
        if (AMODE == 0) {
            constexpr int ITERS = (BM * BK / 8) / 256;
            #pragma unroll
            for (int it = 0; it < ITERS; it++) {
                int idx = it * 256 + tid;
                int cg = idx % (BK / 8), r = idx / (BK / 8);
                *(short8*)&As[r][cg * 8] =
                    ld8<AF32>(A, (size_t)(i0 + r) * lda + ks + cg * 8);
            }
        } else if (AMODE == 1) {
            constexpr int ITERS = (BM * BK / 8) / 256;
            #pragma unroll
            for (int it = 0; it < ITERS; it++) {
                int idx = it * 256 + tid;
                int cg = idx % (BK / 8), r = idx / (BK / 8);
                float av[8];
                ld8f<AF32>(A, (size_t)(i0 + r) * lda + ks + cg * 8, av);
                float f1v = f1[i0 + r];
                short8 p;
                #pragma unroll
                for (int e = 0; e < 8; e++) {
                    float s = f1v + f2[ks + cg * 8 + e];
                    s = s > 0.f ? s : 0.2f * s;
                    p[e] = f2bf(av[e] * __expf(s));
                }
                *(short8*)&As[r][cg * 8] = p;
            }
        } else { // AMODE 2: As[m][k] = S[ks+k][i0+m], pair-packed k
            constexpr int ITERS = ((BK / 2) * (BM / 8)) / 256;
            #pragma unroll
            for (int it = 0; it < ITERS; it++) {
                int idx = it * 256 + tid;
                int mg = idx % (BM / 8), kp = idx / (BM / 8);
                int k = 2 * kp;
                short8 r0 = ld8<AF32>(A, (size_t)(ks + k) * lda + i0 + mg * 8);
                short8 r1 = ld8<AF32>(A, (size_t)(ks + k + 1) * lda + i0 + mg * 8);
                #pragma unroll
                for (int j = 0; j < 8; j++) {
                    unsigned wv = ((unsigned)(unsigned short)r0[j]) |
                                  (((unsigned)(unsigned short)r1[j]) << 16);
                    *(unsigned*)&As[mg * 8 + j][k] = wv;
                }
            }
        }
        // ---- stage B transposed: Bs[n][k] = B[ks+k][n0+n], pair-packed k ----
        {
            constexpr int ITERS = ((BK / 2) * 16) / 256;
            #pragma unroll
            for (int it = 0; it < ITERS; it++) {
                int idx = it * 256 + tid;
                int ng = idx & 15, kp = idx >> 4;
                int k = 2 * kp;
                short8 r0 = ld8<BF32>(B, (size_t)(ks + k) * ldb + n0 + ng * 8);
                short8 r1 = ld8<BF32>(B, (size_t)(ks + k + 1) * ldb + n0 + ng * 8);
                #pragma unroll
                for (int j = 0; j < 8; j++) {
                    unsigned wv = ((unsigned)(unsigned short)r0[j]) |
                                  (((unsigned)(unsigned short)r1[j]) << 16);
                    *(unsigned*)&Bs[ng * 8 + j][k] = wv;
                }
            }
        }
        __syncthreads();
        // ---- MFMA ----
        #pragma unroll
        for (int kk = 0; kk < BK / 32; kk++) {
            short8 af[FM], bq[4];
            #pragma unroll
            for (int m = 0; m < FM; m++)
                af[m] = *(const short8*)&As[wr * (BM / 2) + m * 16 + (lane & 15)]
                                           [kk * 32 + (lane >> 4) * 8];
            #pragma unroll
            for (int n = 0; n < 4; n++)
                bq[n] = *(const short8*)&Bs[wc * 64 + n * 16 + (lane & 15)]
                                           [kk * 32 + (lane >> 4) * 8];
            #pragma unroll
            for (int m = 0; m < FM; m++)
                #pragma unroll
                for (int n = 0; n < 4; n++)
                    acc[m][n] = __builtin_amdgcn_mfma_f32_16x16x32_bf16(
                        af[m], bq[n], acc[m][n], 0, 0, 0);
        }
    }
    // ---- epilogue (C/D: col = lane&15, row = (lane>>4)*4 + reg) ----
    #pragma unroll
    for (int m = 0; m < FM; m++) {
        #pragma unroll
        for (int n = 0; n < 4; n++) {
            int row0 = i0 + wr * (BM / 2) + m * 16 + ((lane >> 4) << 2);
            int col  = n0 + wc * 64 + n * 16 + (lane & 15);
            #pragma unroll
            for (int r = 0; r < 4; r++) {
                int row = row0 + r;
                float v = acc[m][n][r];
                if (EPI == 0) {
                    ((float*)C)[(size_t)row * ldc + col] = v;
                } else if (EPI == 1) {
                    ((short*)C)[(size_t)row * ldc + col] = f2bf(v);
                } else if (EPI == 2) {
                    float d = denom[row];
                    float z = v / (d > 0.f ? d : 1.f) + bf2f(Hadd[(size_t)row * ldh + col]);
                    z = z > 0.f ? z : (__expf(z) - 1.f); // elu
                    ((short*)C)[(size_t)row * ldc + col] = f2bf(z);
                } else {
                    atomicAdd(&((float*)C)[(size_t)row * ldc + col], v);
                }
            }
        }
    }
}

// f1g[i] = h_g[i,:] . a_g[:F], f2g[i] = h_g[i,:] . a_g[F:]   (h bf16, a f32)
__launch_bounds__(256)
__global__ void compute_f_k(const short* __restrict__ h1, const short* __restrict__ h2,
                            const float* __restrict__ ae, const float* __restrict__ aa,
                            float* __restrict__ f11, float* __restrict__ f21,
                            float* __restrict__ f12, float* __restrict__ f22) {
    int row = blockIdx.x, t = threadIdx.x;
    float s11 = 0.f, s21 = 0.f, s12 = 0.f, s22 = 0.f;
    if (t < 128) {
        float hv = bf2f(h1[(size_t)row * 128 + t]);
        s11 = hv * ae[t];
        s21 = hv * ae[128 + t];
    }
    #pragma unroll
    for (int q = 0; q < 4; q++) {
        int f = t + q * 256;
        float hv = bf2f(h2[(size_t)row * 1024 + f]);
        s12 += hv * aa[f];
        s22 += hv * aa[1024 + f];
    }
    __shared__ float red[4][4];
    s11 = wred_sum(s11); s21 = wred_sum(s21);
    s12 = wred_sum(s12); s22 = wred_sum(s22);
    int w = t >> 6;
    if ((t & 63) == 0) { red[0][w] = s11; red[1][w] = s21; red[2][w] = s12; red[3][w] = s22; }
    __syncthreads();
    if (t == 0) {
        f11[row] = red[0][0] + red[0][1] + red[0][2] + red[0][3];
        f21[row] = red[1][0] + red[1][1] + red[1][2] + red[1][3];
        f12[row] = red[2][0] + red[2][1] + red[2][2] + red[2][3];
        f22[row] = red[3][0] + red[3][1] + red[3][2] + red[3][3];
    }
}

// denom_g[i] = sum_j adj_ij * exp(leakyrelu(f1g[i]+f2g[j])). One block per row.
__launch_bounds__(256)
__global__ void stats_k(const float* __restrict__ adj,
                        const float* __restrict__ f11, const float* __restrict__ f21,
                        const float* __restrict__ f12, const float* __restrict__ f22,
                        float* __restrict__ den1, float* __restrict__ den2) {
    int row = blockIdx.x, t = threadIdx.x;
    float a1 = f11[row], a2 = f12[row];
    float d1 = 0.f, d2 = 0.f;
    const float* arow = adj + (size_t)row * 8192;
    #pragma unroll
    for (int it = 0; it < 4; it++) {
        int jb = t * 8 + it * 2048;
        f32x4 v0 = *(const f32x4*)(arow + jb);
        f32x4 v1 = *(const f32x4*)(arow + jb + 4);
        #pragma unroll
        for (int e = 0; e < 8; e++) {
            float a = e < 4 ? v0[e] : v1[e - 4];
            float l1 = a1 + f21[jb + e]; l1 = l1 > 0.f ? l1 : 0.2f * l1;
            float l2 = a2 + f22[jb + e]; l2 = l2 > 0.f ? l2 : 0.2f * l2;
            d1 += a * __expf(l1);
            d2 += a * __expf(l2);
        }
    }
    __shared__ float r1[4], r2[4];
    d1 = wred_sum(d1); d2 = wred_sum(d2);
    if ((t & 63) == 0) { r1[t >> 6] = d1; r2[t >> 6] = d2; }
    __syncthreads();
    if (t == 0) {
        den1[row] = r1[0] + r1[1] + r1[2] + r1[3];
        den2[row] = r2[0] + r2[1] + r2[2] + r2[3];
    }
}

// s_l row = softmax( elu(Y2/den2 + h2) ). Writes f32 to d_out and bf16 to ws.
__launch_bounds__(256)
__global__ void episoft_k(const float* __restrict__ Y2, const float* __restrict__ den2,
                          const short* __restrict__ h2, float* __restrict__ slo,
                          short* __restrict__ slb) {
    int row = blockIdx.x, t = threadIdx.x;
    float d = den2[row];
    d = d > 0.f ? d : 1.f;
    float v[4], mx = -1e30f;
    #pragma unroll
    for (int q = 0; q < 4; q++) {
        int j = t + q * 256;
        float a = Y2[(size_t)row * 1024 + j] / d + bf2f(h2[(size_t)row * 1024 + j]);
        a = a > 0.f ? a : (__expf(a) - 1.f);
        v[q] = a;
        mx = fmaxf(mx, a);
    }
    __shared__ float sred[4];
    __shared__ float sbc;
    mx = wred_max(mx);
    if ((t & 63) == 0) sred[t >> 6] = mx;
    __syncthreads();
    if (t == 0) sbc = fmaxf(fmaxf(sred[0], sred[1]), fmaxf(sred[2], sred[3]));
    __syncthreads();
    mx = sbc;
    float s = 0.f;
    #pragma unroll
    for (int q = 0; q < 4; q++) { v[q] = __expf(v[q] - mx); s += v[q]; }
    s = wred_sum(s);
    if ((t & 63) == 0) sred[t >> 6] = s;
    __syncthreads();
    if (t == 0) sbc = sred[0] + sred[1] + sred[2] + sred[3];
    __syncthreads();
    float inv = 1.f / sbc;
    #pragma unroll
    for (int q = 0; q < 4; q++) {
        float sv = v[q] * inv;
        slo[(size_t)row * 1024 + t + q * 256] = sv;
        slb[(size_t)row * 1024 + t + q * 256] = f2bf(sv);
    }
}

extern "C" void kernel_launch(void* const* d_in, const int* in_sizes, int n_in,
                              void* d_out, int out_size, void* d_ws, size_t ws_size,
                              hipStream_t stream) {
    const float* x   = (const float*)d_in[0];  // [8192,256]
    const float* adj = (const float*)d_in[1];  // [8192,8192]
    const float* We  = (const float*)d_in[2];  // [256,128]
    const float* ae  = (const float*)d_in[3];  // [256,1]
    const float* Wa  = (const float*)d_in[4];  // [256,1024]
    const float* aa  = (const float*)d_in[5];  // [2048,1]
    float* out = (float*)d_out;

    char* w = (char*)d_ws;                       // total ws use: 69 MiB
    short* h1b = (short*)(w);                    // [0,   2M)  bf16 [8192,128]
    short* h2b = (short*)(w + (2u   << 20));     // [2M, 18M)  bf16 [8192,1024]
    float* f11 = (float*)(w + (18u  << 20));
    float* f21 = f11 + 8192;
    float* f12 = f21 + 8192;
    float* f22 = f12 + 8192;
    float* den1 = f22 + 8192;
    float* den2 = den1 + 8192;
    short* zl  = (short*)(w + (19u << 20));      // [19M, 21M) bf16 [8192,128]
    float* Y2  = (float*)(w + (21u << 20));      // [21M, 53M) f32  [8192,1024]
    short* slb = (short*)(w + (53u << 20));      // [53M, 69M) bf16 [8192,1024]
    short* tb  = (short*)(w + (21u << 20));      // reuses Y2 region after episoft

    float* xo  = out;                            // xnext [1024,128] f32
    float* ao  = out + 131072;                   // anext [1024,1024] f32
    float* slo = out + 131072 + 1048576;         // s_l   [8192,1024] f32

    // zero the atomic-accumulated outputs (replays start from poisoned d_out)
    hipMemsetAsync(out, 0, (size_t)(131072 + 1048576) * 4, stream);

    // h1 = x @ We  (M=8192,K=256,N=128)
    gemm_k<128, 64, 0, 1, 1, 1><<<dim3(1, 64, 1), 256, 0, stream>>>(
        x, We, h1b, 256, 128, 128, 256, nullptr, nullptr, nullptr, nullptr, 0);
    // h2 = x @ Wa  (N=1024)
    gemm_k<128, 64, 0, 1, 1, 1><<<dim3(8, 64, 1), 256, 0, stream>>>(
        x, Wa, h2b, 256, 1024, 1024, 256, nullptr, nullptr, nullptr, nullptr, 0);
    // f vectors
    compute_f_k<<<dim3(8192), 256, 0, stream>>>(h1b, h2b, ae, aa, f11, f21, f12, f22);
    // denominators (one adj pass, both GATs)
    stats_k<<<dim3(8192), 256, 0, stream>>>(adj, f11, f21, f12, f22, den1, den2);
    // GAT1 fused: z_l = elu(P1@h1/den1 + h1)  (M=8192,N=128,K=8192)
    gemm_k<32, 64, 1, 2, 1, 0><<<dim3(1, 256, 1), 256, 0, stream>>>(
        adj, h1b, zl, 8192, 128, 128, 8192, f11, f21, den1, h1b, 128);
    // GAT2 main: Y2 = P2@h2 (f32)  (M=8192,N=1024,K=8192)
    gemm_k<128, 64, 1, 0, 1, 0><<<dim3(8, 64, 1), 256, 0, stream>>>(
        adj, h2b, Y2, 8192, 1024, 1024, 8192, f12, f22, nullptr, nullptr, 0);
    // s_l = softmax(elu(Y2/den2 + h2)) -> d_out (f32) + ws (bf16)
    episoft_k<<<dim3(8192), 256, 0, stream>>>(Y2, den2, h2b, slo, slb);
    // t = adj @ s_l  (M=8192,N=1024,K=8192) -> bf16 (overwrites Y2 region)
    gemm_k<128, 64, 0, 1, 1, 0><<<dim3(8, 64, 1), 256, 0, stream>>>(
        adj, slb, tb, 8192, 1024, 1024, 8192, nullptr, nullptr, nullptr, nullptr, 0);
    // anext = s_l^T @ t  (M=1024,N=1024,K=8192, split-K x8) -> d_out atomics
    gemm_k<128, 64, 2, 3, 0, 0><<<dim3(8, 8, 8), 256, 0, stream>>>(
        slb, tb, ao, 1024, 1024, 1024, 1024, nullptr, nullptr, nullptr, nullptr, 0);
    // xnext = s_l^T @ z_l  (M=1024,N=128,K=8192, split-K x32) -> d_out atomics
    gemm_k<128, 64, 2, 3, 0, 0><<<dim3(1, 8, 32), 256, 0, stream>>>(
        slb, zl, xo, 1024, 128, 128, 256, nullptr, nullptr, nullptr, nullptr, 0);
}

// Round 3
// 851.535 us; speedup vs baseline: 1.6289x; 1.6289x over previous
//
#include <hip/hip_runtime.h>
#include <hip/hip_bf16.h>

// BatchedDiffPool on MI355X. Inputs f32, outputs f32; internal bf16 MFMA.
//
// Pipeline:
//  h1=x@We, h2=x@Wa -> f-vectors -> E/F = exp(f), exp(0.2f) ->
//  prepass over adj: den1,den2 (+ adjb,P1b,P2b bf16 if ws allows) ->
//  Y1 = P1@h1 (split-K) -> z_l = elu(Y1/den1 + h1)
//  Y2 = P2@h2 -> s_l = softmax(elu(Y2/den2 + h2)) -> d_out(f32) + ws(bf16)
//  t = adj@s_l ; anext = s_l^T@t ; xnext = s_l^T@z_l (split-K atomics to d_out)
//
// Key trick: exp(leakyrelu(f1+f2)) = (a>1 ? a : b), a=E1[i]*E2[j], b=F1[i]*F2[j]
// (a>1 <=> f1+f2>0 exactly; no transcendentals in any hot loop).
// LDS: 128B row stride + XOR-16B-block swizzle (blk ^ (row^row>>3)&7) ->
// conflict-free ds_read_b128 / staggered pair-pack writes.

#define DI __device__ __forceinline__

typedef __attribute__((ext_vector_type(8))) short short8;
typedef __attribute__((ext_vector_type(4))) float f32x4;

static DI float bf2f(short s) {
    union { unsigned u; float f; } c;
    c.u = ((unsigned)(unsigned short)s) << 16;
    return c.f;
}
static DI short f2bf(float f) {                       // RTN-even
    union { float f; unsigned u; } c; c.f = f;
    unsigned r = (c.u + 0x7FFFu + ((c.u >> 16) & 1u)) >> 16;
    return (short)(unsigned short)r;
}
static DI short f2bf_tr(float f) {                    // truncate (exact for 0/1)
    union { float f; unsigned u; } c; c.f = f;
    return (short)(unsigned short)(c.u >> 16);
}
// load 8 consecutive elements as bf16 shorts. F32: 0=bf16, 1=f32 RTN, 2=f32 trunc
template <int F32>
static DI short8 ld8(const void* base, size_t off) {
    if (F32 == 0) return *(const short8*)((const short*)base + off);
    const float* p = (const float*)base + off;
    f32x4 a = *(const f32x4*)p;
    f32x4 b = *(const f32x4*)(p + 4);
    short8 v;
    #pragma unroll
    for (int e = 0; e < 4; e++) {
        v[e]     = (F32 == 1) ? f2bf(a[e]) : f2bf_tr(a[e]);
        v[4 + e] = (F32 == 1) ? f2bf(b[e]) : f2bf_tr(b[e]);
    }
    return v;
}
static DI float wred_sum(float v) {
    #pragma unroll
    for (int o = 32; o > 0; o >>= 1) v += __shfl_down(v, o, 64);
    return v;
}
static DI float wred_max(float v) {
    #pragma unroll
    for (int o = 32; o > 0; o >>= 1) v = fmaxf(v, __shfl_down(v, o, 64));
    return v;
}
static DI int swz8(int row, int blk) { return blk ^ ((row ^ (row >> 3)) & 7); }
static DI unsigned pack2(short lo, short hi) {
    return ((unsigned)(unsigned short)lo) | (((unsigned)(unsigned short)hi) << 16);
}

// ---------------------------------------------------------------------------
// 256-thread (4-wave, 2x2) MFMA GEMM tile. BN=128, BK=64 fixed.
// AMODE: 0 = A row-major (bf16/f32 per AF32)
//        1 = A generated: P_ik = (adj_ik>0) * (a>1?a:b), a=E1[i]E2[k], b=F1[i]F2[k]
//        2 = A = S^T, S row-major [K][lda]
// EPI:   0 = f32 store   1 = bf16 store   3 = f32 atomicAdd (split-K)
// SWZX:  XCD-aware remap (requires grid (8,64))
// ---------------------------------------------------------------------------
template <int BM, int AMODE, int EPI, int AF32, int BF32, int SWZX>
__launch_bounds__(256)
__global__ void gemm_k(const void* __restrict__ A, const void* __restrict__ B,
                       void* __restrict__ C, int lda, int ldb, int ldc, int kcount,
                       const float* __restrict__ E1, const float* __restrict__ F1,
                       const float* __restrict__ E2, const float* __restrict__ F2) {
    __shared__ short As[BM][64];
    __shared__ short Bs[128][64];

    int bx = blockIdx.x, by = blockIdx.y;
    if (SWZX) { // grid must be (8,64): give each XCD 8 consecutive m-panels
        int lid = blockIdx.x + blockIdx.y * 8;
        int c = lid & 7, s = lid >> 3;
        by = c * 8 + (s >> 3);
        bx = s & 7;
    }
    const int tid  = threadIdx.x;
    const int lane = tid & 63;
    const int w    = tid >> 6;
    const int wr   = w >> 1, wc = w & 1;
    const int i0   = by * BM;
    const int n0   = bx * 128;
    const int k0   = blockIdx.z * kcount;

    const int FM = BM / 32;
    f32x4 acc[FM][4];
    #pragma unroll
    for (int m = 0; m < FM; m++)
        #pragma unroll
        for (int n = 0; n < 4; n++) acc[m][n] = (f32x4){0.f, 0.f, 0.f, 0.f};

    for (int ks = k0; ks < k0 + kcount; ks += 64) {
        __syncthreads();
        // ---- stage A ----
        if (AMODE == 0) {
            #pragma unroll
            for (int it = 0; it < BM / 32; it++) {
                int idx = it * 256 + tid;
                int cg = idx & 7, r = idx >> 3;
                *(short8*)&As[r][swz8(r, cg) * 8] =
                    ld8<AF32>(A, (size_t)(i0 + r) * lda + ks + cg * 8);
            }
        } else if (AMODE == 1) {
            #pragma unroll
            for (int it = 0; it < BM / 32; it++) {
                int idx = it * 256 + tid;
                int cg = idx & 7, r = idx >> 3;
                const float* ap = (const float*)A + (size_t)(i0 + r) * lda + ks + cg * 8;
                f32x4 a0 = *(const f32x4*)ap, a1 = *(const f32x4*)(ap + 4);
                float e1r = E1[i0 + r], f1r = F1[i0 + r];
                const float* e2p = E2 + ks + cg * 8;
                const float* f2p = F2 + ks + cg * 8;
                f32x4 e20 = *(const f32x4*)e2p, e21 = *(const f32x4*)(e2p + 4);
                f32x4 f20 = *(const f32x4*)f2p, f21 = *(const f32x4*)(f2p + 4);
                short8 p;
                #pragma unroll
                for (int e = 0; e < 8; e++) {
                    float av = e < 4 ? a0[e] : a1[e - 4];
                    float ev = e < 4 ? e20[e] : e21[e - 4];
                    float fv = e < 4 ? f20[e] : f21[e - 4];
                    float aa = e1r * ev, bb = f1r * fv;
                    float x = aa > 1.f ? aa : bb;
                    p[e] = f2bf(av > 0.f ? x : 0.f);
                }
                *(short8*)&As[r][swz8(r, cg) * 8] = p;
            }
        } else { // AMODE 2: As[m][k] = S[ks+k][i0+m], pair-packed k
            #pragma unroll
            for (int it = 0; it < BM / 64; it++) {
                int idx = it * 256 + tid;
                int mg = idx % (BM / 8), kp = idx / (BM / 8);
                int k = 2 * kp;
                short8 r0 = ld8<AF32>(A, (size_t)(ks + k) * lda + i0 + mg * 8);
                short8 r1 = ld8<AF32>(A, (size_t)(ks + k + 1) * lda + i0 + mg * 8);
                #pragma unroll
                for (int j = 0; j < 8; j++) {
                    int row = mg * 8 + j;
                    *(unsigned*)&As[row][swz8(row, k >> 3) * 8 + (k & 7)] =
                        pack2(r0[j], r1[j]);
                }
            }
        }
        // ---- stage B transposed: Bs[n][k] = B[ks+k][n0+n], pair-packed ----
        #pragma unroll
        for (int it = 0; it < 2; it++) {
            int idx = it * 256 + tid;
            int ng = idx & 15, kp = idx >> 4;
            int k = 2 * kp;
            short8 r0 = ld8<BF32>(B, (size_t)(ks + k) * ldb + n0 + ng * 8);
            short8 r1 = ld8<BF32>(B, (size_t)(ks + k + 1) * ldb + n0 + ng * 8);
            #pragma unroll
            for (int j = 0; j < 8; j++) {
                int row = ng * 8 + j;
                *(unsigned*)&Bs[row][swz8(row, k >> 3) * 8 + (k & 7)] =
                    pack2(r0[j], r1[j]);
            }
        }
        __syncthreads();
        // ---- MFMA ----
        #pragma unroll
        for (int kk = 0; kk < 2; kk++) {
            short8 af[FM], bq[4];
            #pragma unroll
            for (int m = 0; m < FM; m++) {
                int ar = wr * (BM / 2) + m * 16 + (lane & 15);
                int ab = kk * 4 + (lane >> 4);
                af[m] = *(const short8*)&As[ar][swz8(ar, ab) * 8];
            }
            #pragma unroll
            for (int n = 0; n < 4; n++) {
                int br = wc * 64 + n * 16 + (lane & 15);
                int bb = kk * 4 + (lane >> 4);
                bq[n] = *(const short8*)&Bs[br][swz8(br, bb) * 8];
            }
            #pragma unroll
            for (int m = 0; m < FM; m++)
                #pragma unroll
                for (int n = 0; n < 4; n++)
                    acc[m][n] = __builtin_amdgcn_mfma_f32_16x16x32_bf16(
                        af[m], bq[n], acc[m][n], 0, 0, 0);
        }
    }
    // ---- epilogue (C/D: col = lane&15, row = (lane>>4)*4 + reg) ----
    #pragma unroll
    for (int m = 0; m < FM; m++) {
        #pragma unroll
        for (int n = 0; n < 4; n++) {
            int row0 = i0 + wr * (BM / 2) + m * 16 + ((lane >> 4) << 2);
            int col  = n0 + wc * 64 + n * 16 + (lane & 15);
            #pragma unroll
            for (int r = 0; r < 4; r++) {
                int row = row0 + r;
                float v = acc[m][n][r];
                if (EPI == 0)      ((float*)C)[(size_t)row * ldc + col] = v;
                else if (EPI == 1) ((short*)C)[(size_t)row * ldc + col] = f2bf(v);
                else               atomicAdd(&((float*)C)[(size_t)row * ldc + col], v);
            }
        }
    }
}

// f1g[i] = h_g[i,:] . a_g[:F], f2g[i] = h_g[i,:] . a_g[F:]
__launch_bounds__(256)
__global__ void compute_f_k(const short* __restrict__ h1, const short* __restrict__ h2,
                            const float* __restrict__ ae, const float* __restrict__ aa,
                            float* __restrict__ f11, float* __restrict__ f21,
                            float* __restrict__ f12, float* __restrict__ f22) {
    int row = blockIdx.x, t = threadIdx.x;
    float s11 = 0.f, s21 = 0.f, s12 = 0.f, s22 = 0.f;
    if (t < 128) {
        float hv = bf2f(h1[(size_t)row * 128 + t]);
        s11 = hv * ae[t];
        s21 = hv * ae[128 + t];
    }
    #pragma unroll
    for (int q = 0; q < 4; q++) {
        int f = t + q * 256;
        float hv = bf2f(h2[(size_t)row * 1024 + f]);
        s12 += hv * aa[f];
        s22 += hv * aa[1024 + f];
    }
    __shared__ float red[4][4];
    s11 = wred_sum(s11); s21 = wred_sum(s21);
    s12 = wred_sum(s12); s22 = wred_sum(s22);
    int w = t >> 6;
    if ((t & 63) == 0) { red[0][w] = s11; red[1][w] = s21; red[2][w] = s12; red[3][w] = s22; }
    __syncthreads();
    if (t == 0) {
        f11[row] = red[0][0] + red[0][1] + red[0][2] + red[0][3];
        f21[row] = red[1][0] + red[1][1] + red[1][2] + red[1][3];
        f12[row] = red[2][0] + red[2][1] + red[2][2] + red[2][3];
        f22[row] = red[3][0] + red[3][1] + red[3][2] + red[3][3];
    }
}

// E/F vectors: E = exp(f), F = exp(0.2 f) for all four f-vectors
__launch_bounds__(256)
__global__ void evec_k(const float* __restrict__ f11, const float* __restrict__ f21,
                       const float* __restrict__ f12, const float* __restrict__ f22,
                       float* __restrict__ E11, float* __restrict__ F11,
                       float* __restrict__ E21, float* __restrict__ F21,
                       float* __restrict__ E12, float* __restrict__ F12,
                       float* __restrict__ E22, float* __restrict__ F22) {
    int i = blockIdx.x * 256 + threadIdx.x;
    if (i >= 8192) return;
    float a = f11[i], b = f21[i], c = f12[i], d = f22[i];
    E11[i] = __expf(a); F11[i] = __expf(0.2f * a);
    E21[i] = __expf(b); F21[i] = __expf(0.2f * b);
    E12[i] = __expf(c); F12[i] = __expf(0.2f * c);
    E22[i] = __expf(d); F22[i] = __expf(0.2f * d);
}

// One adj pass: den1/den2; WRITES=1 also emits adjb, P1b, P2b (bf16).
template <int WRITES>
__launch_bounds__(256)
__global__ void prepass_k(const float* __restrict__ adj,
                          const float* __restrict__ E11, const float* __restrict__ F11,
                          const float* __restrict__ E21, const float* __restrict__ F21,
                          const float* __restrict__ E12, const float* __restrict__ F12,
                          const float* __restrict__ E22, const float* __restrict__ F22,
                          float* __restrict__ den1, float* __restrict__ den2,
                          short* __restrict__ adjb, short* __restrict__ P1b,
                          short* __restrict__ P2b) {
    int row = blockIdx.x, t = threadIdx.x;
    float e1r = E11[row], f1r = F11[row];
    float e2r = E12[row], f2r = F12[row];
    float d1 = 0.f, d2 = 0.f;
    const float* arow = adj + (size_t)row * 8192;
    #pragma unroll
    for (int it = 0; it < 4; it++) {
        int jb = (it * 256 + t) * 8;
        f32x4 a0 = *(const f32x4*)(arow + jb), a1 = *(const f32x4*)(arow + jb + 4);
        f32x4 eA0 = *(const f32x4*)(E21 + jb), eA1 = *(const f32x4*)(E21 + jb + 4);
        f32x4 fA0 = *(const f32x4*)(F21 + jb), fA1 = *(const f32x4*)(F21 + jb + 4);
        f32x4 eB0 = *(const f32x4*)(E22 + jb), eB1 = *(const f32x4*)(E22 + jb + 4);
        f32x4 fB0 = *(const f32x4*)(F22 + jb), fB1 = *(const f32x4*)(F22 + jb + 4);
        short8 ab, p1v, p2v;
        #pragma unroll
        for (int e = 0; e < 8; e++) {
            float av = e < 4 ? a0[e] : a1[e - 4];
            float eA = e < 4 ? eA0[e] : eA1[e - 4];
            float fA = e < 4 ? fA0[e] : fA1[e - 4];
            float eB = e < 4 ? eB0[e] : eB1[e - 4];
            float fB = e < 4 ? fB0[e] : fB1[e - 4];
            float aa = e1r * eA, bb = f1r * fA;
            float x1 = aa > 1.f ? aa : bb;
            float cc = e2r * eB, dd = f2r * fB;
            float x2 = cc > 1.f ? cc : dd;
            float p1 = av > 0.f ? x1 : 0.f;
            float p2 = av > 0.f ? x2 : 0.f;
            d1 += p1; d2 += p2;
            if (WRITES) { ab[e] = f2bf_tr(av); p1v[e] = f2bf(p1); p2v[e] = f2bf(p2); }
        }
        if (WRITES) {
            *(short8*)(adjb + (size_t)row * 8192 + jb) = ab;
            *(short8*)(P1b  + (size_t)row * 8192 + jb) = p1v;
            *(short8*)(P2b  + (size_t)row * 8192 + jb) = p2v;
        }
    }
    __shared__ float r1[4], r2[4];
    d1 = wred_sum(d1); d2 = wred_sum(d2);
    if ((t & 63) == 0) { r1[t >> 6] = d1; r2[t >> 6] = d2; }
    __syncthreads();
    if (t == 0) {
        den1[row] = r1[0] + r1[1] + r1[2] + r1[3];
        den2[row] = r2[0] + r2[1] + r2[2] + r2[3];
    }
}

// z_l = bf16( elu(Y1/den1 + h1) )   (8192x128, 8 elems/thread)
__launch_bounds__(256)
__global__ void epi_gat1_k(const float* __restrict__ Y1, const float* __restrict__ den1,
                           const short* __restrict__ h1, short* __restrict__ zl) {
    int idx = blockIdx.x * 256 + threadIdx.x;
    int base = idx * 8;
    int row = base >> 7;
    float d = den1[row]; d = d > 0.f ? d : 1.f;
    f32x4 y0 = *(const f32x4*)(Y1 + base), y1 = *(const f32x4*)(Y1 + base + 4);
    short8 hv = *(const short8*)(h1 + base);
    short8 o;
    #pragma unroll
    for (int e = 0; e < 8; e++) {
        float z = (e < 4 ? y0[e] : y1[e - 4]) / d + bf2f(hv[e]);
        z = z > 0.f ? z : (__expf(z) - 1.f);
        o[e] = f2bf(z);
    }
    *(short8*)(zl + base) = o;
}

// s_l row = softmax( elu(Y2/den2 + h2) ). f32 to d_out, bf16 to ws.
__launch_bounds__(256)
__global__ void episoft_k(const float* __restrict__ Y2, const float* __restrict__ den2,
                          const short* __restrict__ h2, float* __restrict__ slo,
                          short* __restrict__ slb) {
    int row = blockIdx.x, t = threadIdx.x;
    float d = den2[row];
    d = d > 0.f ? d : 1.f;
    float v[4], mx = -1e30f;
    #pragma unroll
    for (int q = 0; q < 4; q++) {
        int j = t + q * 256;
        float a = Y2[(size_t)row * 1024 + j] / d + bf2f(h2[(size_t)row * 1024 + j]);
        a = a > 0.f ? a : (__expf(a) - 1.f);
        v[q] = a;
        mx = fmaxf(mx, a);
    }
    __shared__ float sred[4];
    __shared__ float sbc;
    mx = wred_max(mx);
    if ((t & 63) == 0) sred[t >> 6] = mx;
    __syncthreads();
    if (t == 0) sbc = fmaxf(fmaxf(sred[0], sred[1]), fmaxf(sred[2], sred[3]));
    __syncthreads();
    mx = sbc;
    float s = 0.f;
    #pragma unroll
    for (int q = 0; q < 4; q++) { v[q] = __expf(v[q] - mx); s += v[q]; }
    s = wred_sum(s);
    if ((t & 63) == 0) sred[t >> 6] = s;
    __syncthreads();
    if (t == 0) sbc = sred[0] + sred[1] + sred[2] + sred[3];
    __syncthreads();
    float inv = 1.f / sbc;
    #pragma unroll
    for (int q = 0; q < 4; q++) {
        float sv = v[q] * inv;
        slo[(size_t)row * 1024 + t + q * 256] = sv;
        slb[(size_t)row * 1024 + t + q * 256] = f2bf(sv);
    }
}

extern "C" void kernel_launch(void* const* d_in, const int* in_sizes, int n_in,
                              void* d_out, int out_size, void* d_ws, size_t ws_size,
                              hipStream_t stream) {
    const float* x   = (const float*)d_in[0];  // [8192,256]
    const float* adj = (const float*)d_in[1];  // [8192,8192]
    const float* We  = (const float*)d_in[2];  // [256,128]
    const float* ae  = (const float*)d_in[3];  // [256,1] (2*128)
    const float* Wa  = (const float*)d_in[4];  // [256,1024]
    const float* aa  = (const float*)d_in[5];  // [2048,1]
    float* out = (float*)d_out;

    char* w = (char*)d_ws;
    short* h1b = (short*)(w);                    // 2 MiB  bf16 [8192,128]
    short* h2b = (short*)(w + (2u   << 20));     // 16 MiB bf16 [8192,1024]
    float* f11 = (float*)(w + (18u  << 20));     // 14 x 32 KiB vectors
    float* f21 = f11 + 8192;  float* f12 = f21 + 8192; float* f22 = f12 + 8192;
    float* den1 = f22 + 8192; float* den2 = den1 + 8192;
    float* E11 = den2 + 8192; float* F11 = E11 + 8192;
    float* E21 = F11 + 8192;  float* F21 = E21 + 8192;
    float* E12 = F21 + 8192;  float* F12 = E12 + 8192;
    float* E22 = F12 + 8192;  float* F22 = E22 + 8192;
    short* zl  = (short*)(w + (19u << 20));      // 2 MiB  bf16 [8192,128]
    float* Y1f = (float*)(w + (21u << 20));      // 4 MiB  f32  [8192,128]
    float* Y2  = (float*)(w + (25u << 20));      // 32 MiB f32  [8192,1024]
    short* slb = (short*)(w + (57u << 20));      // 16 MiB bf16 [8192,1024]
    bool full = ws_size >= (size_t)(512u) * 1024 * 1024;
    short* tb   = full ? (short*)(w + (73u << 20)) : (short*)Y2; // 16 MiB bf16
    short* adjb = (short*)(w + (96u  << 20));    // 128 MiB (FULL only)
    short* P1b  = (short*)(w + (224u << 20));    // 128 MiB (FULL only)
    short* P2b  = (short*)(w + (352u << 20));    // 128 MiB (FULL only)

    float* xo  = out;                            // xnext [1024,128] f32
    float* ao  = out + 131072;                   // anext [1024,1024] f32
    float* slo = out + 131072 + 1048576;         // s_l   [8192,1024] f32

    // zero atomic-accumulated buffers (graph replays start from poison)
    hipMemsetAsync(out, 0, (size_t)(131072 + 1048576) * 4, stream);
    hipMemsetAsync(Y1f, 0, (size_t)8192 * 128 * 4, stream);

    // h1 = x @ We ; h2 = x @ Wa   (f32 in, bf16 out)
    gemm_k<128, 0, 1, 1, 1, 0><<<dim3(1, 64, 1), 256, 0, stream>>>(
        x, We, h1b, 256, 128, 128, 256, nullptr, nullptr, nullptr, nullptr);
    gemm_k<128, 0, 1, 1, 1, 1><<<dim3(8, 64, 1), 256, 0, stream>>>(
        x, Wa, h2b, 256, 1024, 1024, 256, nullptr, nullptr, nullptr, nullptr);
    compute_f_k<<<dim3(8192), 256, 0, stream>>>(h1b, h2b, ae, aa, f11, f21, f12, f22);
    evec_k<<<dim3(32), 256, 0, stream>>>(f11, f21, f12, f22,
        E11, F11, E21, F21, E12, F12, E22, F22);

    if (full) {
        prepass_k<1><<<dim3(8192), 256, 0, stream>>>(adj,
            E11, F11, E21, F21, E12, F12, E22, F22, den1, den2, adjb, P1b, P2b);
        // Y1 = P1 @ h1 (split-K x4)
        gemm_k<128, 0, 3, 0, 0, 0><<<dim3(1, 64, 4), 256, 0, stream>>>(
            P1b, h1b, Y1f, 8192, 128, 128, 2048, nullptr, nullptr, nullptr, nullptr);
        epi_gat1_k<<<dim3(512), 256, 0, stream>>>(Y1f, den1, h1b, zl);
        // Y2 = P2 @ h2
        gemm_k<128, 0, 0, 0, 0, 1><<<dim3(8, 64, 1), 256, 0, stream>>>(
            P2b, h2b, Y2, 8192, 1024, 1024, 8192, nullptr, nullptr, nullptr, nullptr);
        episoft_k<<<dim3(8192), 256, 0, stream>>>(Y2, den2, h2b, slo, slb);
        // t = adj @ s_l
        gemm_k<128, 0, 1, 0, 0, 1><<<dim3(8, 64, 1), 256, 0, stream>>>(
            adjb, slb, tb, 8192, 1024, 1024, 8192, nullptr, nullptr, nullptr, nullptr);
    } else {
        prepass_k<0><<<dim3(8192), 256, 0, stream>>>(adj,
            E11, F11, E21, F21, E12, F12, E22, F22, den1, den2,
            nullptr, nullptr, nullptr);
        gemm_k<128, 1, 3, 1, 0, 0><<<dim3(1, 64, 4), 256, 0, stream>>>(
            adj, h1b, Y1f, 8192, 128, 128, 2048, E11, F11, E21, F21);
        epi_gat1_k<<<dim3(512), 256, 0, stream>>>(Y1f, den1, h1b, zl);
        gemm_k<128, 1, 0, 1, 0, 1><<<dim3(8, 64, 1), 256, 0, stream>>>(
            adj, h2b, Y2, 8192, 1024, 1024, 8192, E12, F12, E22, F22);
        episoft_k<<<dim3(8192), 256, 0, stream>>>(Y2, den2, h2b, slo, slb);
        gemm_k<128, 0, 1, 2, 0, 1><<<dim3(8, 64, 1), 256, 0, stream>>>(
            adj, slb, tb, 8192, 1024, 1024, 8192, nullptr, nullptr, nullptr, nullptr);
    }
    // anext = s_l^T @ t  (split-K x8, atomics into d_out)
    gemm_k<128, 2, 3, 0, 0, 0><<<dim3(8, 8, 8), 256, 0, stream>>>(
        slb, tb, ao, 1024, 1024, 1024, 1024, nullptr, nullptr, nullptr, nullptr);
    // xnext = s_l^T @ z_l  (split-K x32, atomics into d_out)
    gemm_k<128, 2, 3, 0, 0, 0><<<dim3(1, 8, 32), 256, 0, stream>>>(
        slb, zl, xo, 1024, 128, 128, 256, nullptr, nullptr, nullptr, nullptr);
}